// Round 1
// baseline (1465.497 us; speedup 1.0000x reference)
//
#include <hip/hip_runtime.h>

// AGG layer: out[n] = mean_{e: dst[e]==n} (src_emb[src[e]] + edge_emb[e]),  D=64 fp32.
// Stage 1: memset out + deg.  Stage 2: edge scatter w/ atomics.  Stage 3: divide by deg.

#define D 64

__global__ __launch_bounds__(256) void edge_scatter_kernel(
    const float* __restrict__ src_emb,
    const float* __restrict__ edge_emb,
    const int*   __restrict__ src_idx,
    const int*   __restrict__ dst_idx,
    float*       __restrict__ out,
    int*         __restrict__ deg,
    int E)
{
    int tid  = blockIdx.x * blockDim.x + threadIdx.x;
    int e    = tid >> 4;        // 16 threads per edge (16 x float4 = 64 floats)
    int lane = tid & 15;
    if (e >= E) return;

    int s = src_idx[e];
    int d = dst_idx[e];

    // edge_emb: 256 B contiguous per edge; 4 consecutive edges per wave -> 1 KiB coalesced
    const float4 a = *(const float4*)(src_emb  + (size_t)s * D + lane * 4);
    const float4 b = *(const float4*)(edge_emb + (size_t)e * D + lane * 4);

    float4 m;
    m.x = a.x + b.x; m.y = a.y + b.y; m.z = a.z + b.z; m.w = a.w + b.w;

    float* o = out + (size_t)d * D + lane * 4;
    atomicAdd(o + 0, m.x);
    atomicAdd(o + 1, m.y);
    atomicAdd(o + 2, m.z);
    atomicAdd(o + 3, m.w);

    if (lane == 0) atomicAdd(deg + d, 1);
}

__global__ __launch_bounds__(256) void divide_deg_kernel(
    float* __restrict__ out,
    const int* __restrict__ deg,
    int N)
{
    int tid  = blockIdx.x * blockDim.x + threadIdx.x;
    int n    = tid >> 4;        // 16 threads per node row
    int lane = tid & 15;
    if (n >= N) return;

    int dg = deg[n];
    float inv = 1.0f / (float)(dg > 1 ? dg : 1);

    float4* o = (float4*)(out + (size_t)n * D + lane * 4);
    float4 v = *o;
    v.x *= inv; v.y *= inv; v.z *= inv; v.w *= inv;
    *o = v;
}

extern "C" void kernel_launch(void* const* d_in, const int* in_sizes, int n_in,
                              void* d_out, int out_size, void* d_ws, size_t ws_size,
                              hipStream_t stream) {
    const float* src_emb  = (const float*)d_in[0];   // [N, 64]
    const float* edge_emb = (const float*)d_in[1];   // [E, 64]
    const int*   src_idx  = (const int*)d_in[2];     // [E]
    const int*   dst_idx  = (const int*)d_in[3];     // [E]
    // d_in[4] = num_nodes scalar (unused; derived from out_size)

    const int E = in_sizes[2];
    const int N = out_size / D;

    float* out = (float*)d_out;
    int*   deg = (int*)d_ws;                          // N ints of scratch

    hipMemsetAsync(d_out, 0, (size_t)out_size * sizeof(float), stream);
    hipMemsetAsync(deg,   0, (size_t)N * sizeof(int), stream);

    {
        long long threads = (long long)E * 16;
        int grid = (int)((threads + 255) / 256);
        edge_scatter_kernel<<<grid, 256, 0, stream>>>(src_emb, edge_emb, src_idx, dst_idx,
                                                      out, deg, E);
    }
    {
        long long threads = (long long)N * 16;
        int grid = (int)((threads + 255) / 256);
        divide_deg_kernel<<<grid, 256, 0, stream>>>(out, deg, N);
    }
}

// Round 3
// 798.856 us; speedup vs baseline: 1.8345x; 1.8345x over previous
//
#include <hip/hip_runtime.h>

// AGG layer: out[n] = mean_{e: dst[e]==n} (src_emb[src[e]] + edge_emb[e]),  D=64 fp32.
// Round 3 (= round 2 + compile fix): device-side counting sort by dst +
// per-node gather-reduce (zero fp32 atomics).
//
// ws layout (ints): [0, N+1)   offsets (exclusive prefix sum, offsets[N]=E)
//                   [N+1, 2N+1) cursor  (hist counts, then running scatter cursor)
//                   [2N+1, ...) edge_order (E ints)

#define D 64

__global__ __launch_bounds__(256) void hist_kernel(
    const int* __restrict__ dst_idx, int* __restrict__ count, int E)
{
    int e = blockIdx.x * blockDim.x + threadIdx.x;
    if (e < E) atomicAdd(count + dst_idx[e], 1);
}

// Single-workgroup exclusive prefix scan over N counts -> offsets[0..N].
__global__ __launch_bounds__(1024) void scan_kernel(
    const int* __restrict__ count, int* __restrict__ offsets, int N)
{
    __shared__ int sums[1024];
    const int t = threadIdx.x;
    const int chunk = (N + 1023) / 1024;
    const int lo = t * chunk;
    const int hi = (lo + chunk < N) ? lo + chunk : N;

    int s = 0;
    for (int i = lo; i < hi; ++i) s += count[i];
    sums[t] = s;
    __syncthreads();

    // Hillis-Steele inclusive scan in LDS
    for (int off = 1; off < 1024; off <<= 1) {
        int v = 0;
        if (t >= off) v = sums[t - off];
        __syncthreads();
        if (t >= off) sums[t] += v;
        __syncthreads();
    }

    int run = (t == 0) ? 0 : sums[t - 1];
    for (int i = lo; i < hi; ++i) { offsets[i] = run; run += count[i]; }
    if (t == 1023) offsets[N] = run;   // == E
}

__global__ __launch_bounds__(256) void scatter_kernel(
    const int* __restrict__ dst_idx, int* __restrict__ cursor,
    int* __restrict__ edge_order, int E)
{
    int e = blockIdx.x * blockDim.x + threadIdx.x;
    if (e < E) {
        int pos = atomicAdd(cursor + dst_idx[e], 1);
        edge_order[pos] = e;
    }
}

// One 16-lane group per node; lane owns one float4 column slice.
__global__ __launch_bounds__(256) void reduce_kernel(
    const float* __restrict__ src_emb,
    const float* __restrict__ edge_emb,
    const int*   __restrict__ src_idx,
    const int*   __restrict__ offsets,
    const int*   __restrict__ edge_order,
    float*       __restrict__ out,
    int N)
{
    int tid  = blockIdx.x * blockDim.x + threadIdx.x;
    int n    = tid >> 4;
    int lane = tid & 15;
    if (n >= N) return;

    const int beg = offsets[n];
    const int end = offsets[n + 1];

    float4 acc = make_float4(0.f, 0.f, 0.f, 0.f);
    const int col = lane * 4;

    for (int i = beg; i < end; ++i) {
        const int e = edge_order[i];
        const int s = src_idx[e];
        const float4 a = *(const float4*)(src_emb  + (size_t)s * D + col);
        const float4 b = *(const float4*)(edge_emb + (size_t)e * D + col);
        acc.x += a.x + b.x;
        acc.y += a.y + b.y;
        acc.z += a.z + b.z;
        acc.w += a.w + b.w;
    }

    const int deg = end - beg;
    const float inv = (deg > 0) ? (1.0f / (float)deg) : 0.0f;
    float4 r;
    r.x = acc.x * inv; r.y = acc.y * inv; r.z = acc.z * inv; r.w = acc.w * inv;
    *(float4*)(out + (size_t)n * D + col) = r;
}

extern "C" void kernel_launch(void* const* d_in, const int* in_sizes, int n_in,
                              void* d_out, int out_size, void* d_ws, size_t ws_size,
                              hipStream_t stream) {
    const float* src_emb  = (const float*)d_in[0];   // [N, 64]
    const float* edge_emb = (const float*)d_in[1];   // [E, 64]
    const int*   src_idx  = (const int*)d_in[2];     // [E]
    const int*   dst_idx  = (const int*)d_in[3];     // [E]

    const int E = in_sizes[2];
    const int N = out_size / D;

    float* out = (float*)d_out;

    int* offsets    = (int*)d_ws;            // N+1
    int* cursor     = offsets + (N + 1);     // N
    int* edge_order = cursor + N;            // E

    // 1) histogram into cursor
    (void)hipMemsetAsync(cursor, 0, (size_t)N * sizeof(int), stream);
    hist_kernel<<<(E + 255) / 256, 256, 0, stream>>>(dst_idx, cursor, E);

    // 2) exclusive scan -> offsets
    scan_kernel<<<1, 1024, 0, stream>>>(cursor, offsets, N);

    // 3) scatter edge ids (cursor := offsets copy, consumed as running cursor)
    (void)hipMemcpyAsync(cursor, offsets, (size_t)N * sizeof(int),
                         hipMemcpyDeviceToDevice, stream);
    scatter_kernel<<<(E + 255) / 256, 256, 0, stream>>>(dst_idx, cursor, edge_order, E);

    // 4) gather-reduce, divide fused, every output row written exactly once
    {
        long long threads = (long long)N * 16;
        int grid = (int)((threads + 255) / 256);
        reduce_kernel<<<grid, 256, 0, stream>>>(src_emb, edge_emb, src_idx,
                                                offsets, edge_order, out, N);
    }
}

// Round 4
// 716.972 us; speedup vs baseline: 2.0440x; 1.1142x over previous
//
#include <hip/hip_runtime.h>

// AGG layer: out[n] = mean_{e: dst[e]==n} (src_emb[src[e]] + edge_emb[e]),  D=64 fp32.
// Round 4: materialize dst-sorted messages (streaming scatter), then contiguous
// per-node reduce. No dependent-load chains in hot loops; no fp32 atomics.
//
// ws layout (ints): offsets[N+1] | counts[N] | cursor[N] | blockSums[1024] |
//                   blockBase[1024] | (pad to 16B) | msg[E*64 floats, 320 MB]

#define D 64
#define SCAN_BLK 1024   // elements per scan block (256 thr x 4)

__global__ __launch_bounds__(256) void hist_kernel(
    const int* __restrict__ dst_idx, int* __restrict__ counts, int E)
{
    int e = blockIdx.x * blockDim.x + threadIdx.x;
    if (e < E) atomicAdd(counts + dst_idx[e], 1);
}

// K1: per-block sums of counts
__global__ __launch_bounds__(256) void scan_partial_kernel(
    const int* __restrict__ counts, int* __restrict__ blockSums, int N)
{
    __shared__ int red[256];
    const int t = threadIdx.x, b = blockIdx.x;
    const int base = b * SCAN_BLK + t * 4;
    int s = 0;
    #pragma unroll
    for (int k = 0; k < 4; ++k) { int i = base + k; if (i < N) s += counts[i]; }
    red[t] = s; __syncthreads();
    for (int off = 128; off; off >>= 1) {
        if (t < off) red[t] += red[t + off];
        __syncthreads();
    }
    if (t == 0) blockSums[b] = red[0];
}

// K2: exclusive scan of block sums (numBlocks <= 1024); writes offsets[N]=E
__global__ __launch_bounds__(1024) void scan_sums_kernel(
    const int* __restrict__ blockSums, int* __restrict__ blockBase,
    int numBlocks, int* __restrict__ offsets, int N)
{
    __shared__ int s[1024];
    const int t = threadIdx.x;
    int v = (t < numBlocks) ? blockSums[t] : 0;
    s[t] = v; __syncthreads();
    for (int off = 1; off < 1024; off <<= 1) {
        int u = (t >= off) ? s[t - off] : 0;
        __syncthreads();
        if (t >= off) s[t] += u;
        __syncthreads();
    }
    if (t < numBlocks) blockBase[t] = (t == 0) ? 0 : s[t - 1];
    if (t == numBlocks - 1) offsets[N] = s[t];   // total == E
}

// K3: final exclusive scan; writes offsets[i] AND cursor[i] (scatter cursor copy)
__global__ __launch_bounds__(256) void scan_final_kernel(
    const int* __restrict__ counts, const int* __restrict__ blockBase,
    int* __restrict__ offsets, int* __restrict__ cursor, int N)
{
    __shared__ int sc[256];
    const int t = threadIdx.x, b = blockIdx.x;
    const int base = b * SCAN_BLK + t * 4;
    int local[4];
    int s = 0;
    #pragma unroll
    for (int k = 0; k < 4; ++k) {
        int i = base + k;
        int c = (i < N) ? counts[i] : 0;
        local[k] = s; s += c;
    }
    sc[t] = s; __syncthreads();
    for (int off = 1; off < 256; off <<= 1) {
        int u = (t >= off) ? sc[t - off] : 0;
        __syncthreads();
        if (t >= off) sc[t] += u;
        __syncthreads();
    }
    const int thrBase = blockBase[b] + ((t == 0) ? 0 : sc[t - 1]);
    #pragma unroll
    for (int k = 0; k < 4; ++k) {
        int i = base + k;
        if (i < N) { int v = thrBase + local[k]; offsets[i] = v; cursor[i] = v; }
    }
}

// Pass A: compute msg in original edge order (coalesced edge_emb), scatter to
// dst-sorted slot. One int atomic per edge (lane 0), broadcast via shfl.
__global__ __launch_bounds__(256) void msg_scatter_kernel(
    const float* __restrict__ src_emb,
    const float* __restrict__ edge_emb,
    const int*   __restrict__ src_idx,
    const int*   __restrict__ dst_idx,
    int*         __restrict__ cursor,
    float*       __restrict__ msg,
    int E)
{
    int tid  = blockIdx.x * blockDim.x + threadIdx.x;
    int e    = tid >> 4;
    int lane = tid & 15;
    if (e >= E) return;

    int pos = 0;
    if (lane == 0) pos = atomicAdd(cursor + dst_idx[e], 1);
    pos = __shfl(pos, 0, 16);

    const int s   = src_idx[e];
    const int col = lane * 4;
    const float4 a = *(const float4*)(src_emb  + (size_t)s * D + col);
    const float4 b = *(const float4*)(edge_emb + (size_t)e * D + col);
    float4 m;
    m.x = a.x + b.x; m.y = a.y + b.y; m.z = a.z + b.z; m.w = a.w + b.w;
    *(float4*)(msg + (size_t)pos * D + col) = m;
}

// Pass B: contiguous streaming reduce per node, fused divide.
__global__ __launch_bounds__(256) void reduce_sorted_kernel(
    const int*   __restrict__ offsets,
    const float* __restrict__ msg,
    float*       __restrict__ out,
    int N)
{
    int tid  = blockIdx.x * blockDim.x + threadIdx.x;
    int n    = tid >> 4;
    int lane = tid & 15;
    if (n >= N) return;

    const int beg = offsets[n];
    const int end = offsets[n + 1];
    const int col = lane * 4;

    float4 acc0 = make_float4(0.f, 0.f, 0.f, 0.f);
    float4 acc1 = make_float4(0.f, 0.f, 0.f, 0.f);

    int i = beg;
    for (; i + 1 < end; i += 2) {
        const float4 a = *(const float4*)(msg + (size_t)i       * D + col);
        const float4 b = *(const float4*)(msg + (size_t)(i + 1) * D + col);
        acc0.x += a.x; acc0.y += a.y; acc0.z += a.z; acc0.w += a.w;
        acc1.x += b.x; acc1.y += b.y; acc1.z += b.z; acc1.w += b.w;
    }
    if (i < end) {
        const float4 a = *(const float4*)(msg + (size_t)i * D + col);
        acc0.x += a.x; acc0.y += a.y; acc0.z += a.z; acc0.w += a.w;
    }

    const int deg = end - beg;
    const float inv = (deg > 0) ? (1.0f / (float)deg) : 0.0f;
    float4 r;
    r.x = (acc0.x + acc1.x) * inv;
    r.y = (acc0.y + acc1.y) * inv;
    r.z = (acc0.z + acc1.z) * inv;
    r.w = (acc0.w + acc1.w) * inv;
    *(float4*)(out + (size_t)n * D + col) = r;
}

extern "C" void kernel_launch(void* const* d_in, const int* in_sizes, int n_in,
                              void* d_out, int out_size, void* d_ws, size_t ws_size,
                              hipStream_t stream) {
    const float* src_emb  = (const float*)d_in[0];   // [N, 64]
    const float* edge_emb = (const float*)d_in[1];   // [E, 64]
    const int*   src_idx  = (const int*)d_in[2];     // [E]
    const int*   dst_idx  = (const int*)d_in[3];     // [E]

    const int E = in_sizes[2];
    const int N = out_size / D;

    float* out = (float*)d_out;

    int* wsi       = (int*)d_ws;
    int* offsets   = wsi;                    // N+1
    int* counts    = offsets + (N + 1);      // N
    int* cursor    = counts + N;             // N
    int* blockSums = cursor + N;             // 1024
    int* blockBase = blockSums + 1024;       // 1024
    size_t hdr = (size_t)(N + 1) + N + N + 1024 + 1024;
    hdr = (hdr + 3) & ~(size_t)3;            // 16B-align msg
    float* msg = (float*)(wsi + hdr);        // E*64 floats

    const int numBlocks = (N + SCAN_BLK - 1) / SCAN_BLK;

    (void)hipMemsetAsync(counts, 0, (size_t)N * sizeof(int), stream);
    hist_kernel<<<(E + 255) / 256, 256, 0, stream>>>(dst_idx, counts, E);
    scan_partial_kernel<<<numBlocks, 256, 0, stream>>>(counts, blockSums, N);
    scan_sums_kernel<<<1, 1024, 0, stream>>>(blockSums, blockBase, numBlocks, offsets, N);
    scan_final_kernel<<<numBlocks, 256, 0, stream>>>(counts, blockBase, offsets, cursor, N);

    {
        long long threads = (long long)E * 16;
        int grid = (int)((threads + 255) / 256);
        msg_scatter_kernel<<<grid, 256, 0, stream>>>(src_emb, edge_emb, src_idx, dst_idx,
                                                     cursor, msg, E);
    }
    {
        long long threads = (long long)N * 16;
        int grid = (int)((threads + 255) / 256);
        reduce_sorted_kernel<<<grid, 256, 0, stream>>>(offsets, msg, out, N);
    }
}

// Round 5
// 624.198 us; speedup vs baseline: 2.3478x; 1.1486x over previous
//
#include <hip/hip_runtime.h>

// AGG layer: out[n] = mean_{e: dst[e]==n} (src_emb[src[e]] + edge_emb[e]),  D=64 fp32.
// Round 5: CSR build + dst-sorted {edge,src} PAIR list (8 B/edge, 10 MB) instead
// of materialized 320 MB messages. Reduce = one wave per node: bulk-load pair
// chunk, v_readlane broadcast -> wave-uniform row base -> two coalesced 256 B
// row loads per edge, scalar fp32 acc per lane. Zero fp32 atomics.
//
// ws ints: offsets[N+1] | counts[N] | cursor[N] | blockSums[1024] | blockBase[1024]
//          | (pad to 8B) | pairs[E] (int2)

#define D 64
#define SCAN_BLK 1024   // elements per scan block (256 thr x 4)

__global__ __launch_bounds__(256) void hist_kernel(
    const int* __restrict__ dst_idx, int* __restrict__ counts, int E)
{
    int e = blockIdx.x * blockDim.x + threadIdx.x;
    if (e < E) atomicAdd(counts + dst_idx[e], 1);
}

__global__ __launch_bounds__(256) void scan_partial_kernel(
    const int* __restrict__ counts, int* __restrict__ blockSums, int N)
{
    __shared__ int red[256];
    const int t = threadIdx.x, b = blockIdx.x;
    const int base = b * SCAN_BLK + t * 4;
    int s = 0;
    #pragma unroll
    for (int k = 0; k < 4; ++k) { int i = base + k; if (i < N) s += counts[i]; }
    red[t] = s; __syncthreads();
    for (int off = 128; off; off >>= 1) {
        if (t < off) red[t] += red[t + off];
        __syncthreads();
    }
    if (t == 0) blockSums[b] = red[0];
}

__global__ __launch_bounds__(1024) void scan_sums_kernel(
    const int* __restrict__ blockSums, int* __restrict__ blockBase,
    int numBlocks, int* __restrict__ offsets, int N)
{
    __shared__ int s[1024];
    const int t = threadIdx.x;
    int v = (t < numBlocks) ? blockSums[t] : 0;
    s[t] = v; __syncthreads();
    for (int off = 1; off < 1024; off <<= 1) {
        int u = (t >= off) ? s[t - off] : 0;
        __syncthreads();
        if (t >= off) s[t] += u;
        __syncthreads();
    }
    if (t < numBlocks) blockBase[t] = (t == 0) ? 0 : s[t - 1];
    if (t == numBlocks - 1) offsets[N] = s[t];   // total == E
}

__global__ __launch_bounds__(256) void scan_final_kernel(
    const int* __restrict__ counts, const int* __restrict__ blockBase,
    int* __restrict__ offsets, int* __restrict__ cursor, int N)
{
    __shared__ int sc[256];
    const int t = threadIdx.x, b = blockIdx.x;
    const int base = b * SCAN_BLK + t * 4;
    int local[4];
    int s = 0;
    #pragma unroll
    for (int k = 0; k < 4; ++k) {
        int i = base + k;
        int c = (i < N) ? counts[i] : 0;
        local[k] = s; s += c;
    }
    sc[t] = s; __syncthreads();
    for (int off = 1; off < 256; off <<= 1) {
        int u = (t >= off) ? sc[t - off] : 0;
        __syncthreads();
        if (t >= off) sc[t] += u;
        __syncthreads();
    }
    const int thrBase = blockBase[b] + ((t == 0) ? 0 : sc[t - 1]);
    #pragma unroll
    for (int k = 0; k < 4; ++k) {
        int i = base + k;
        if (i < N) { int v = thrBase + local[k]; offsets[i] = v; cursor[i] = v; }
    }
}

// Scatter {edge, src} pairs into dst-sorted order. 1 thread/edge, 8 B writes.
__global__ __launch_bounds__(256) void pair_scatter_kernel(
    const int* __restrict__ src_idx,
    const int* __restrict__ dst_idx,
    int*       __restrict__ cursor,
    int2*      __restrict__ pairs,
    int E)
{
    int e = blockIdx.x * blockDim.x + threadIdx.x;
    if (e >= E) return;
    int pos = atomicAdd(cursor + dst_idx[e], 1);
    pairs[pos] = make_int2(e, src_idx[e]);
}

// One wave (64 lanes) per node. Lane l holds column l of the accumulator.
__global__ __launch_bounds__(256) void reduce_kernel(
    const float* __restrict__ src_emb,
    const float* __restrict__ edge_emb,
    const int2*  __restrict__ pairs,
    const int*   __restrict__ offsets,
    float*       __restrict__ out,
    int N)
{
    const int wave = (blockIdx.x * blockDim.x + threadIdx.x) >> 6;
    const int lane = threadIdx.x & 63;
    if (wave >= N) return;

    const int beg = offsets[wave];
    const int end = offsets[wave + 1];

    float acc = 0.0f;

    for (int base = beg; base < end; base += 64) {
        const int cnt = min(64, end - base);
        int2 pr = make_int2(0, 0);
        if (lane < cnt) pr = pairs[base + lane];

        int j = 0;
        // unroll by 2: two edges -> four independent 256 B row loads in flight
        for (; j + 1 < cnt; j += 2) {
            const int e0 = __builtin_amdgcn_readlane(pr.x, j);
            const int s0 = __builtin_amdgcn_readlane(pr.y, j);
            const int e1 = __builtin_amdgcn_readlane(pr.x, j + 1);
            const int s1 = __builtin_amdgcn_readlane(pr.y, j + 1);
            const float v0 = edge_emb[(size_t)e0 * D + lane];
            const float v1 = src_emb [(size_t)s0 * D + lane];
            const float v2 = edge_emb[(size_t)e1 * D + lane];
            const float v3 = src_emb [(size_t)s1 * D + lane];
            acc += (v0 + v1) + (v2 + v3);
        }
        if (j < cnt) {
            const int e0 = __builtin_amdgcn_readlane(pr.x, j);
            const int s0 = __builtin_amdgcn_readlane(pr.y, j);
            acc += edge_emb[(size_t)e0 * D + lane] + src_emb[(size_t)s0 * D + lane];
        }
    }

    const int deg = end - beg;
    const float inv = (deg > 0) ? (1.0f / (float)deg) : 0.0f;
    out[(size_t)wave * D + lane] = acc * inv;
}

extern "C" void kernel_launch(void* const* d_in, const int* in_sizes, int n_in,
                              void* d_out, int out_size, void* d_ws, size_t ws_size,
                              hipStream_t stream) {
    const float* src_emb  = (const float*)d_in[0];   // [N, 64]
    const float* edge_emb = (const float*)d_in[1];   // [E, 64]
    const int*   src_idx  = (const int*)d_in[2];     // [E]
    const int*   dst_idx  = (const int*)d_in[3];     // [E]

    const int E = in_sizes[2];
    const int N = out_size / D;

    float* out = (float*)d_out;

    int* wsi       = (int*)d_ws;
    int* offsets   = wsi;                    // N+1
    int* counts    = offsets + (N + 1);      // N
    int* cursor    = counts + N;             // N
    int* blockSums = cursor + N;             // 1024
    int* blockBase = blockSums + 1024;       // 1024
    size_t hdr = (size_t)(N + 1) + N + N + 1024 + 1024;
    hdr = (hdr + 1) & ~(size_t)1;            // 8-B align pairs
    int2* pairs = (int2*)(wsi + hdr);        // E int2

    const int numBlocks = (N + SCAN_BLK - 1) / SCAN_BLK;

    (void)hipMemsetAsync(counts, 0, (size_t)N * sizeof(int), stream);
    hist_kernel<<<(E + 255) / 256, 256, 0, stream>>>(dst_idx, counts, E);
    scan_partial_kernel<<<numBlocks, 256, 0, stream>>>(counts, blockSums, N);
    scan_sums_kernel<<<1, 1024, 0, stream>>>(blockSums, blockBase, numBlocks, offsets, N);
    scan_final_kernel<<<numBlocks, 256, 0, stream>>>(counts, blockBase, offsets, cursor, N);

    pair_scatter_kernel<<<(E + 255) / 256, 256, 0, stream>>>(src_idx, dst_idx,
                                                             cursor, pairs, E);
    {
        // 4 waves per 256-thread block, one wave per node
        int grid = (N + 3) / 4;
        reduce_kernel<<<grid, 256, 0, stream>>>(src_emb, edge_emb, pairs,
                                                offsets, out, N);
    }
}